// Round 3
// baseline (467.899 us; speedup 1.0000x reference)
//
#include <hip/hip_runtime.h>

// Problem dims (fixed by setup_inputs): B=4096, A=2048, F=8
#define NB    4096
#define AP1   2049
#define FEAT  8
#define ROWF  (AP1 * FEAT)        // 16392 floats per sample
#define G2_BLOCKS 2048
#define G2_THREADS 256
#define G0_BLOCKS (NB / 256)      // 16

// ws layout (int/float words):
//   [WS_RS    .. WS_RS+NB+1)   int   row_start[NB+1] (exclusive prefix of counts)
//   [WS_CNT   .. WS_CNT+NB)    int   counts[NB]
//   [WS_P2    .. +G2_BLOCKS)   float phase-2 per-block partial sums
//   [WS_P0C   .. +16)          float phase-0 per-block count-loss partials
//   [WS_P0V   .. +16)          float phase-0 per-block n_valid partials
// Every slot is written unconditionally each launch -> poison-safe.
#define WS_RS   0
#define WS_CNT  4112              // keep counts 16B-aligned
#define WS_P2   (WS_CNT + NB)
#define WS_P0C  (WS_P2 + G2_BLOCKS)
#define WS_P0V  (WS_P0C + 16)

__device__ __forceinline__ float block_reduce_256(float v, float* sm) {
    #pragma unroll
    for (int o = 32; o > 0; o >>= 1) v += __shfl_down(v, o, 64);
    const int wid  = threadIdx.x >> 6;
    const int lane = threadIdx.x & 63;
    if (lane == 0) sm[wid] = v;
    __syncthreads();
    return sm[0] + sm[1] + sm[2] + sm[3];   // valid in all threads after sync
}

// Phase 0: gather counts + count-loss partials. 16 blocks x 256.
__global__ __launch_bounds__(256) void phase0_gather(
        const float* __restrict__ pred, const float* __restrict__ targ,
        int* __restrict__ wsi, float* __restrict__ wsf) {
    const int b = blockIdx.x * 256 + threadIdx.x;
    const float tc = targ[(size_t)b * ROWF];
    const float pc = pred[(size_t)b * ROWF];
    const int cnt = (int)tc;
    wsi[WS_CNT + b] = cnt;
    const float d = pc - tc;

    __shared__ float sm[4];
    const float closs = block_reduce_256(d * d, sm);
    __syncthreads();
    const float nval = block_reduce_256(cnt > 0 ? 1.0f : 0.0f, sm);
    if (threadIdx.x == 0) {
        wsf[WS_P0C + blockIdx.x] = closs;
        wsf[WS_P0V + blockIdx.x] = nval;
    }
}

// Phase 1: exclusive prefix sum of counts -> row_start. 1 block x 1024.
__global__ __launch_bounds__(1024) void phase1_scan(int* __restrict__ wsi) {
    const int t = threadIdx.x;
    // thread t owns counts[4t .. 4t+3]
    const int4 c = *(const int4*)&wsi[WS_CNT + 4 * t];
    const int s_own = c.x + c.y + c.z + c.w;

    __shared__ int sc[1024];
    sc[t] = s_own;
    __syncthreads();
    #pragma unroll
    for (int off = 1; off < 1024; off <<= 1) {
        int v = (t >= off) ? sc[t - off] : 0;
        __syncthreads();
        sc[t] += v;
        __syncthreads();
    }
    const int excl = sc[t] - s_own;   // exclusive prefix of thread sums

    int4 rs;
    rs.x = excl;
    rs.y = excl + c.x;
    rs.z = rs.y + c.y;
    rs.w = rs.z + c.z;
    *(int4*)&wsi[WS_RS + 4 * t] = rs;
    if (t == 1023) wsi[WS_RS + NB] = sc[1023];   // total valid rows
}

// Phase 2: uniform grid-stride over valid rows; binary search row->sample in LDS.
__global__ __launch_bounds__(G2_THREADS) void phase2_main(
        const float* __restrict__ pred, const float* __restrict__ targ,
        const int* __restrict__ wsi, float* __restrict__ wsf) {
    __shared__ int rs[NB + 1];
    __shared__ float sm[4];
    for (int i = threadIdx.x; i <= NB; i += G2_THREADS)
        rs[i] = wsi[WS_RS + i];
    __syncthreads();

    const int T = rs[NB];
    float s = 0.0f;
    const int stride = G2_BLOCKS * G2_THREADS;

    for (int r = blockIdx.x * G2_THREADS + threadIdx.x; r < T; r += stride) {
        // binary search: rs[b] <= r < rs[b+1]
        int lo = 0, hi = NB;
        #pragma unroll
        for (int it = 0; it < 12; ++it) {
            const int mid = (lo + hi) >> 1;
            if (rs[mid] <= r) lo = mid; else hi = mid;
        }
        const int b = lo;
        const int local = r - rs[b];
        const int cnt8 = (rs[b + 1] - rs[b]) * FEAT;
        const size_t base = (size_t)b * ROWF + FEAT + (size_t)local * FEAT;

        const float4 a0 = *(const float4*)(pred + base);
        const float4 a1 = *(const float4*)(pred + base + 4);
        const float4 c0 = *(const float4*)(targ + base);
        const float4 c1 = *(const float4*)(targ + base + 4);

        float dx, dy, dz, dw, sq;
        dx = a0.x - c0.x; dy = a0.y - c0.y; dz = a0.z - c0.z; dw = a0.w - c0.w;
        sq = dx * dx + dy * dy + dz * dz + dw * dw;
        dx = a1.x - c1.x; dy = a1.y - c1.y; dz = a1.z - c1.z; dw = a1.w - c1.w;
        sq += dx * dx + dy * dy + dz * dz + dw * dw;

        s += sq / (float)cnt8;
    }

    const float total = block_reduce_256(s, sm);
    if (threadIdx.x == 0) wsf[WS_P2 + blockIdx.x] = total;
}

// Phase 3: final reduce. 1 block x 256.
__global__ __launch_bounds__(256) void phase3_final(
        const float* __restrict__ wsf, float* __restrict__ out) {
    float s = 0.0f;
    for (int i = threadIdx.x; i < G2_BLOCKS; i += 256) s += wsf[WS_P2 + i];
    float cl = 0.0f, nv = 0.0f;
    if (threadIdx.x < 16) {
        cl = wsf[WS_P0C + threadIdx.x];
        nv = wsf[WS_P0V + threadIdx.x];
    }
    __shared__ float sm[4];
    const float mse_sum = block_reduce_256(s, sm);
    __syncthreads();
    const float count_sum = block_reduce_256(cl, sm);
    __syncthreads();
    const float n_valid = block_reduce_256(nv, sm);

    if (threadIdx.x == 0) {
        const float count_loss = count_sum * (1.0f / (float)NB);
        const float atl = (n_valid > 0.0f) ? (mse_sum / n_valid) : 0.0f;
        out[0] = count_loss + 2.0f * atl;   // W_ACTION_COUNT=1, W_ACTION_TENSOR=2
    }
}

extern "C" void kernel_launch(void* const* d_in, const int* in_sizes, int n_in,
                              void* d_out, int out_size, void* d_ws, size_t ws_size,
                              hipStream_t stream) {
    const float* pred = (const float*)d_in[0];
    const float* targ = (const float*)d_in[1];
    float* out = (float*)d_out;
    int*   wsi = (int*)d_ws;
    float* wsf = (float*)d_ws;

    phase0_gather<<<G0_BLOCKS, 256, 0, stream>>>(pred, targ, wsi, wsf);
    phase1_scan<<<1, 1024, 0, stream>>>(wsi);
    phase2_main<<<G2_BLOCKS, G2_THREADS, 0, stream>>>(pred, targ, wsi, wsf);
    phase3_final<<<1, 256, 0, stream>>>(wsf, out);
}